// Round 9
// baseline (285.158 us; speedup 1.0000x reference)
//
#include <hip/hip_runtime.h>
#include <math.h>

// B=4, C1=128, C2=256, H=W=64, HW=4096, k=3, N=9
// ws layout (float units):
//   xp   : [4][256][4096] f32  (CHW, for K2)     @ 0          (4194304 f32)
//   off  : [4][18][4096]  f32                    @ 4194304    (294912 f32)
//   xph  : [4][4096][256] bf16 (HWC, for K3)     @ 4489216    (2097152 f32-slots)
//   wTb  : [9][256o][256c] bf16                  @ 6586368    (294912 f32-slots)
//   part : [8][4][18][4096] f32                  @ 6881280    (2359296 f32)
#define XP_F   0
#define OFF_F  4194304
#define XPH_F  4489216
#define WTB_F  6586368
#define PART_F 6881280

typedef short bf16x8 __attribute__((ext_vector_type(8)));
typedef float f32x4 __attribute__((ext_vector_type(4)));

__device__ inline unsigned short f2b(float f) {
    union { float f; unsigned u; } v; v.f = f;
    unsigned r = v.u + 0x7FFF + ((v.u >> 16) & 1);   // RNE
    return (unsigned short)(r >> 16);
}
__device__ inline float b2f(unsigned short h) {
    union { unsigned u; float f; } v; v.u = ((unsigned)h) << 16; return v.f;
}

// ---------------------------------------------------------------------------
// K0: wTb[n][o][c] = bf16(dcn[o][c][n]). grid 2304 x 256
__global__ __launch_bounds__(256) void k0_prep(const float* __restrict__ dcn,
                                               unsigned short* __restrict__ wTb) {
    int idx = blockIdx.x * 256 + threadIdx.x;          // 0 .. 589823
    int n = idx >> 16, o = (idx >> 8) & 255, c = idx & 255;
    wTb[idx] = f2b(dcn[(o * 256 + c) * 9 + n]);
}

// ---------------------------------------------------------------------------
// K1: pointwise conv (128->256) + BN; writes xp (f32 CHW, K2) and xph (bf16 HWC, K3).
__global__ __launch_bounds__(256, 4) void k1_pw_bn(const float* __restrict__ x,
                                                   const float* __restrict__ pw,
                                                   const float* __restrict__ gamma,
                                                   const float* __restrict__ beta,
                                                   const float* __restrict__ mean,
                                                   const float* __restrict__ var,
                                                   float* __restrict__ xp,
                                                   unsigned short* __restrict__ xph) {
    __shared__ float wl[128 * 64];   // [k][c2_local]
    int t = threadIdx.x;
    int m0 = blockIdx.x * 64;
    int b = m0 >> 12;
    int hw = (m0 & 4095) + (t & 63);
    int q = t >> 6;
    int c2base = blockIdx.y * 64;

    // stage weights: idx = kk*64 + c2l (c2l fast) -> LDS writes conflict-free;
    // pw reads strided but pw is 128KB L2-resident.
    for (int i = 0; i < 32; ++i) {
        int idx = t + 256 * i;
        int kk = idx >> 6, c2l = idx & 63;
        wl[idx] = pw[(c2base + c2l) * 128 + kk];
    }
    __syncthreads();

    float acc[16];
#pragma unroll
    for (int i = 0; i < 16; ++i) acc[i] = 0.f;

    const float* xb = x + (b * 128) * 4096 + hw;
    for (int kk = 0; kk < 128; kk += 8) {
        float xv[8];
#pragma unroll
        for (int u = 0; u < 8; ++u) xv[u] = xb[(kk + u) * 4096];
#pragma unroll
        for (int u = 0; u < 8; ++u) {
            const float4* w4 = (const float4*)&wl[(kk + u) * 64 + q * 16];
#pragma unroll
            for (int i = 0; i < 4; ++i) {
                float4 wv = w4[i];
                acc[i * 4 + 0] += xv[u] * wv.x;
                acc[i * 4 + 1] += xv[u] * wv.y;
                acc[i * 4 + 2] += xv[u] * wv.z;
                acc[i * 4 + 3] += xv[u] * wv.w;
            }
        }
    }
    bf16x8 r0, r1;
#pragma unroll
    for (int i = 0; i < 16; ++i) {
        int c2 = c2base + q * 16 + i;
        float s = gamma[c2] * rsqrtf(var[c2] + 1e-5f);
        float v = acc[i] * s + (beta[c2] - mean[c2] * s);
        xp[((b * 256 + c2) << 12) + hw] = v;
        if (i < 8) r0[i] = (short)f2b(v); else r1[i - 8] = (short)f2b(v);
    }
    unsigned short* hb = xph + (((b << 12) + hw) << 8) + c2base + q * 16;
    *(bf16x8*)hb = r0;
    *(bf16x8*)(hb + 8) = r1;
}

// ---------------------------------------------------------------------------
// K2a: 3x3 offset conv (256 -> 18) partial sums, NO atomics.
// grid 2048 x 256: bx = b*512 + h*8 + cs; writes part[cs][b][j][hw].
__global__ __launch_bounds__(256) void k2a_off(const float* __restrict__ xp,
                                               const float* __restrict__ offw,
                                               float* __restrict__ part) {
    __shared__ float xl[3 * 32 * 66];
    __shared__ float wl[9 * 18 * 32];
    int t = threadIdx.x;
    int bx = blockIdx.x;
    int b = bx >> 9, h = (bx >> 3) & 63, cs = bx & 7;
    int w = t & 63, jset = t >> 6;
    const int jbase_a[4] = {0, 5, 10, 14};
    const int jcnt_a[4] = {5, 5, 4, 4};
    int jbase = jbase_a[jset], jcnt = jcnt_a[jset];
    float acc[5] = {0.f, 0.f, 0.f, 0.f, 0.f};
    int cbase = cs * 32;

    for (int idx = t; idx < 3 * 32 * 66; idx += 256) {
        int dy = idx / 2112, rem = idx % 2112;
        int c = rem / 66, col = rem % 66;
        int y = h + dy - 1, wc = col - 1;
        float v = 0.f;
        if ((unsigned)y < 64u && (unsigned)wc < 64u)
            v = xp[((b * 256 + cbase + c) << 12) + y * 64 + wc];
        xl[idx] = v;
    }
    for (int idx = t; idx < 18 * 32 * 9; idx += 256) {
        int j = idx / 288, c = (idx / 9) % 32, tap = idx % 9;
        wl[(tap * 18 + j) * 32 + c] = offw[(j * 256 + cbase + c) * 9 + tap];
    }
    __syncthreads();
#pragma unroll
    for (int tap = 0; tap < 9; ++tap) {
        int dy = tap / 3, dx = tap % 3;
        const float* xrow = &xl[dy * 2112 + (w + dx)];
        const float4* wrow = (const float4*)&wl[(tap * 18 + jbase) * 32];
#pragma unroll
        for (int c4 = 0; c4 < 8; ++c4) {
            float xv0 = xrow[(c4 * 4 + 0) * 66];
            float xv1 = xrow[(c4 * 4 + 1) * 66];
            float xv2 = xrow[(c4 * 4 + 2) * 66];
            float xv3 = xrow[(c4 * 4 + 3) * 66];
#pragma unroll
            for (int jj = 0; jj < 5; ++jj) {
                if (jj < jcnt) {
                    float4 wv = wrow[jj * 8 + c4];
                    acc[jj] += xv0 * wv.x + xv1 * wv.y + xv2 * wv.z + xv3 * wv.w;
                }
            }
        }
    }
    for (int jj = 0; jj < 5; ++jj) {
        if (jj < jcnt)
            part[(((cs * 4 + b) * 18 + jbase + jj) << 12) + h * 64 + w] = acc[jj];
    }
}

// K2b: off[b][j][hw] = off_b[j] + sum_cs part[cs][b][j][hw]. grid 1152 x 256
__global__ __launch_bounds__(256) void k2b_red(const float* __restrict__ part,
                                               const float* __restrict__ offb,
                                               float* __restrict__ off) {
    int i = blockIdx.x * 256 + threadIdx.x;            // 0 .. 294911
    int j = (i >> 12) % 18;
    float s = offb[j];
#pragma unroll
    for (int cs = 0; cs < 8; ++cs) s += part[cs * 294912 + i];
    off[i] = s;
}

// ---------------------------------------------------------------------------
// K3: deformable sampling (HWC gathers) + bf16 MFMA einsum + SiLU.
// 512 thr = 8 waves; tile 32 px x 256 o; wave tile 32 o x 32 px.
// Producer: wave-step (wv,ku) owns ONE frag region F; lane l's data IS
// consumer lane l's fragment (identity) -> write chunk l^(F&7): 64 distinct
// chunks of one 1KB region = conflict-free write AND read.
// sched_barrier(0) pins gathers before the MFMA cluster (T14 for real).
__global__ __launch_bounds__(512, 4) void k3_dcn(const unsigned short* __restrict__ xph,
                                                 const float* __restrict__ off,
                                                 const unsigned short* __restrict__ wTb,
                                                 float* __restrict__ out) {
    __shared__ int   i00[288], i01[288], i10[288], i11[288];
    __shared__ float w00[288], w01[288], w10[288], w11[288];
    __shared__ unsigned short smp[2][16 * 64 * 8];   // [buf][frag][chunk][8]

    int t = threadIdx.x;
    int orig = blockIdx.x;
    int bx = (orig & 7) * 64 + (orig >> 3);      // XCD-bijective swizzle (512%8==0)
    int b = bx >> 7, h = (bx >> 1) & 63, wh = (bx & 1) * 32;
    int wv = t >> 6, l = t & 63;
    const unsigned short* xb = xph + (b << 20);  // batch base (HWC)

    // phase A: sampling params for 9 taps x 32 px; store loc<<8 (ushort offset)
    if (t < 288) {
        int n = t >> 5, p = t & 31;
        int w = wh + p;
        float oy = off[((b * 18 + n) << 12) + h * 64 + w];
        float ox = off[((b * 18 + n + 9) << 12) + h * 64 + w];
        float py = (float)(h + n / 3 - 1) + oy;
        float px = (float)(w + n % 3 - 1) + ox;
        py = fminf(fmaxf(py, 0.f), 63.f);
        px = fminf(fmaxf(px, 0.f), 63.f);
        float fy = floorf(py), fx = floorf(px);
        int y0 = (int)fy, x0 = (int)fx;
        float wy = py - fy, wx = px - fx;
        int y1 = min(y0 + 1, 63), x1 = min(x0 + 1, 63);
        i00[t] = (y0 * 64 + x0) << 8;  i01[t] = (y0 * 64 + x1) << 8;
        i10[t] = (y1 * 64 + x0) << 8;  i11[t] = (y1 * 64 + x1) << 8;
        w00[t] = (1.f - wy) * (1.f - wx);  w01[t] = (1.f - wy) * wx;
        w10[t] = wy * (1.f - wx);          w11[t] = wy * wx;
    }
    __syncthreads();

    // per-thread producer geometry: step ku -> region F, px, channel group
    int pt_p = wv & 1;
    int ks0 = wv >> 1;                            // ku=0: ks0, ku=1: ks0+4
    int px_p = pt_p * 16 + (l & 15);              // pixel this lane samples
    int cgl = l >> 4;                             // 0..3 within k-window

    bf16x8 g[2][4];                               // in-flight gathers (32 VGPR)

    auto stage_issue = [&](int tap) {
        int sb = tap * 32 + px_p;
        int a00 = i00[sb], a01 = i01[sb], a10 = i10[sb], a11 = i11[sb];
#pragma unroll
        for (int ku = 0; ku < 2; ++ku) {
            int ks = ks0 + ku * 4;
            int c = (ks * 4 + cgl) << 3;
            g[ku][0] = *(const bf16x8*)(xb + a00 + c);
            g[ku][1] = *(const bf16x8*)(xb + a01 + c);
            g[ku][2] = *(const bf16x8*)(xb + a10 + c);
            g[ku][3] = *(const bf16x8*)(xb + a11 + c);
        }
    };
    auto stage_write = [&](int tap) {
        int bu = tap & 1;
        int sb = tap * 32 + px_p;
        float b00 = w00[sb], b01 = w01[sb], b10 = w10[sb], b11 = w11[sb];
#pragma unroll
        for (int ku = 0; ku < 2; ++ku) {
            bf16x8 r;
#pragma unroll
            for (int j = 0; j < 8; ++j) {
                float v = b00 * b2f((unsigned short)g[ku][0][j]) +
                          b01 * b2f((unsigned short)g[ku][1][j]) +
                          b10 * b2f((unsigned short)g[ku][2][j]) +
                          b11 * b2f((unsigned short)g[ku][3][j]);
                r[j] = (short)f2b(v);
            }
            int F = pt_p * 8 + ks0 + ku * 4;
            *(bf16x8*)&smp[bu][(F * 64 + (l ^ (F & 7))) << 3] = r;
        }
    };

    // prologue: fill buffer 0
    stage_issue(0);
    __builtin_amdgcn_sched_barrier(0);
    stage_write(0);
    __syncthreads();

    f32x4 acc[2][2];
#pragma unroll
    for (int i = 0; i < 2; ++i)
#pragma unroll
        for (int j = 0; j < 2; ++j) acc[i][j] = (f32x4)0.f;

    int arow = l & 15, areg = l >> 4;            // A: row=o (l&15), k-reg group
    for (int tap = 0; tap < 9; ++tap) {
        if (tap < 8) stage_issue(tap + 1);       // gathers issued...
        __builtin_amdgcn_sched_barrier(0);       // ...and PINNED before MFMA
        int bu = tap & 1;
        const unsigned short* wbase =
            wTb + (tap * 256 + wv * 32 + arow) * 256 + areg * 8;
        __builtin_amdgcn_s_setprio(1);
#pragma unroll
        for (int ks = 0; ks < 8; ++ks) {
            bf16x8 a0 = *(const bf16x8*)(wbase + ks * 32);
            bf16x8 a1 = *(const bf16x8*)(wbase + 16 * 256 + ks * 32);
#pragma unroll
            for (int pt = 0; pt < 2; ++pt) {
                int F = pt * 8 + ks;
                bf16x8 bfr = *(const bf16x8*)
                    &smp[bu][(F * 64 + (l ^ (F & 7))) << 3];
                acc[0][pt] = __builtin_amdgcn_mfma_f32_16x16x32_bf16(a0, bfr, acc[0][pt], 0, 0, 0);
                acc[1][pt] = __builtin_amdgcn_mfma_f32_16x16x32_bf16(a1, bfr, acc[1][pt], 0, 0, 0);
            }
        }
        __builtin_amdgcn_s_setprio(0);
        __builtin_amdgcn_sched_barrier(0);
        if (tap < 8) stage_write(tap + 1);       // bilinear + LDS write after MFMA
        __syncthreads();
    }

    // epilogue: SiLU + store. D: row(o) = (l>>4)*4+j, col(px) = l&15
#pragma unroll
    for (int ot = 0; ot < 2; ++ot)
#pragma unroll
        for (int pt = 0; pt < 2; ++pt) {
            int px = wh + pt * 16 + (l & 15);
#pragma unroll
            for (int j = 0; j < 4; ++j) {
                int o = wv * 32 + ot * 16 + (l >> 4) * 4 + j;
                float a = acc[ot][pt][j];
                out[((b * 256 + o) << 12) + h * 64 + px] = a / (1.f + expf(-a));
            }
        }
}

// ---------------------------------------------------------------------------
extern "C" void kernel_launch(void* const* d_in, const int* in_sizes, int n_in,
                              void* d_out, int out_size, void* d_ws, size_t ws_size,
                              hipStream_t stream) {
    const float* x     = (const float*)d_in[0];
    const float* pw    = (const float*)d_in[1];
    const float* gamma = (const float*)d_in[2];
    const float* beta  = (const float*)d_in[3];
    const float* mean  = (const float*)d_in[4];
    const float* var   = (const float*)d_in[5];
    const float* offw  = (const float*)d_in[6];
    const float* offb  = (const float*)d_in[7];
    const float* dcn   = (const float*)d_in[8];
    float* ws = (float*)d_ws;
    float* xp   = ws + XP_F;
    float* off  = ws + OFF_F;
    unsigned short* xph = (unsigned short*)(ws + XPH_F);
    unsigned short* wTb = (unsigned short*)(ws + WTB_F);
    float* part = ws + PART_F;
    float* out = (float*)d_out;

    hipLaunchKernelGGL(k0_prep, dim3(2304), dim3(256), 0, stream, dcn, wTb);
    hipLaunchKernelGGL(k1_pw_bn, dim3(256, 4), dim3(256), 0, stream,
                       x, pw, gamma, beta, mean, var, xp, xph);
    hipLaunchKernelGGL(k2a_off, dim3(2048), dim3(256), 0, stream, xp, offw, part);
    hipLaunchKernelGGL(k2b_red, dim3(1152), dim3(256), 0, stream, part, offb, off);
    hipLaunchKernelGGL(k3_dcn, dim3(512), dim3(512), 0, stream, xph, off, wTb, out);
}